// Round 13
// baseline (94.154 us; speedup 1.0000x reference)
//
#include <hip/hip_runtime.h>
#include <hip/hip_bf16.h>
#include <stdint.h>
#include <math.h>

// TernaryMobiusLinear: out = mobius( (x @ W) * scale ), x 8192x2048 fp32, W ternary.
// Path: x -> i8 per-row quant; W -> i8 exact; 32x32x32 i8 MFMA GEMM (i32 exact).
// R13: A-only LDS (3x32KB, counted vmcnt), B direct global->reg prefetch (L2-resident Wq).
#define M_DIM 8192
#define K_DIM 2048
#define N_DIM 2048

#define BM 256
#define BN 256
#define BKB 128            // K-tile bytes; A row = 128 B = 8 x 16B chunks
#define NT (K_DIM / BKB)   // 16

typedef __attribute__((ext_vector_type(4))) int int32x4;
typedef __attribute__((ext_vector_type(16))) int int32x16;
typedef __attribute__((ext_vector_type(4))) float float4v;

__device__ __forceinline__ ushort f2bf(float f) {
    uint32_t u = __builtin_bit_cast(uint32_t, f);
    u = (u + 0x7fffu + ((u >> 16) & 1u)) >> 16;
    return (ushort)u;
}

#define GLD16(gp, lp)                                                          \
    __builtin_amdgcn_global_load_lds(                                          \
        (const __attribute__((address_space(1))) void*)(gp),                   \
        (__attribute__((address_space(3))) void*)(lp), 16, 0, 0)

#define BAR()                                                                  \
    do {                                                                       \
        asm volatile("" ::: "memory");                                         \
        __builtin_amdgcn_s_barrier();                                          \
        asm volatile("" ::: "memory");                                         \
    } while (0)

#define VMCNT(n) asm volatile("s_waitcnt vmcnt(" #n ")" ::: "memory")

// ---------------- prepass 1: W (K x N fp32 ternary) -> Wq (N x K i8, transposed) ----------
__global__ __launch_bounds__(256) void transpose_w_i8(const float* __restrict__ W,
                                                      signed char* __restrict__ Wq) {
    __shared__ float tile[32][33];
    const int tb = blockIdx.x;
    const int kb = (tb & 63) * 32;
    const int nb = (tb >> 6) * 32;
    const int tx = threadIdx.x & 31;
    const int ty4 = (threadIdx.x >> 5) * 4;
#pragma unroll
    for (int i = 0; i < 4; i++)
        tile[ty4 + i][tx] = W[(size_t)(kb + ty4 + i) * N_DIM + nb + tx];
    __syncthreads();
    const int r = threadIdx.x >> 3;
    const int c4 = threadIdx.x & 7;
    uint32_t pk = 0;
#pragma unroll
    for (int j = 0; j < 4; j++) {
        const int q = (int)tile[c4 * 4 + j][r];
        pk |= (uint32_t)(q & 255) << (8 * j);
    }
    *(uint32_t*)&Wq[(size_t)(nb + r) * K_DIM + kb + c4 * 4] = pk;
}

// ---------------- prepass 2: x fp32 -> i8 with per-row scale ----------------
__global__ __launch_bounds__(256) void quant_x(const float* __restrict__ X,
                                               signed char* __restrict__ Xq,
                                               float* __restrict__ srow) {
    const int row = blockIdx.x;
    const int t = threadIdx.x;
    const float* p = X + (size_t)row * K_DIM;
    float4v a = *(const float4v*)&p[t * 8];
    float4v b = *(const float4v*)&p[t * 8 + 4];
    float m = 0.f;
#pragma unroll
    for (int j = 0; j < 4; j++) m = fmaxf(m, fmaxf(fabsf(a[j]), fabsf(b[j])));
#pragma unroll
    for (int off = 1; off < 64; off <<= 1) m = fmaxf(m, __shfl_xor(m, off));
    __shared__ float wm[4];
    if ((t & 63) == 0) wm[t >> 6] = m;
    __syncthreads();
    float bm = fmaxf(fmaxf(wm[0], wm[1]), fmaxf(wm[2], wm[3]));
    bm = fmaxf(bm, 1e-8f);
    const float inv = 127.f / bm;
    uint32_t lo = 0, hi = 0;
#pragma unroll
    for (int j = 0; j < 4; j++) {
        const int qa = __float2int_rn(a[j] * inv);
        const int qb = __float2int_rn(b[j] * inv);
        lo |= (uint32_t)(qa & 255) << (8 * j);
        hi |= (uint32_t)(qb & 255) << (8 * j);
    }
    uint32_t* q = (uint32_t*)&Xq[(size_t)row * K_DIM + t * 8];
    q[0] = lo;
    q[1] = hi;
    if (t == 0) srow[row] = bm / 127.f;
}

// ---------------- GEMM: Cb = bf16( (Xq @ Wq^T) * scale ), i32 accum exact ----------------
// 256x256 tile, BKB=128, 8 waves (2M x 4N), per-wave C = 128x64 = 4m x 2n frags of 32x32.
// A: LDS, 3 buffers x 32KB (96 KB); staged via gld_lds with R9's swizzle (verified).
// B: DIRECT global->reg, per-lane 16B loads from L2-resident Wq (4 MB), 1-tile reg prefetch
//    with static double-buffer (2-unrolled loop, rule #20).
// Per-tile issue order: B[t+1](8 loads) -> A[t+2] staging(4 gld_lds) -> compute ->
//   VMCNT(4): FIFO drains A[t+1]+B[t+1] (certified), leaves A[t+2] in flight (2-tile cover).
__global__ __launch_bounds__(512, 1) void gemm_i8(const signed char* __restrict__ Xq,
                                                  const signed char* __restrict__ Wq,
                                                  const float* __restrict__ scale,
                                                  ushort* __restrict__ Cb) {
    __shared__ __align__(16) ushort lds[49152];   // 96 KiB: A bufs @ {0,16384,32768} ushorts

    const int tid = threadIdx.x;
    const int w = tid >> 6;            // wave 0..7
    const int lane = tid & 63;
    const int lrow = lane & 31;
    const int khalf = lane >> 5;       // 0..1: 16B chunk within K=32
    const int rswz = lrow & 7;         // read-side XOR (chunk units) — R9-verified

    // XCD-chunked bijective swizzle (nwg=256, 8 XCDs)
    const int bid = blockIdx.x;
    const int wg = (bid & 7) * 32 + (bid >> 3);
    const int mt = wg >> 3;            // 0..31
    const int nt = wg & 7;             // 0..7
    const int row0 = mt * BM;
    const int col0 = nt * BN;

    const int wr = (w >> 2) * 128;     // wave M offset
    const int wc = (w & 3) * 64;       // wave N offset
    const int whalfA = w >> 2;         // which A half this wave reads

    // A staging geometry (R9-verified): thread covers chunks q = (i*8+w)*64+lane
    int r_[2], c8_[2];
#pragma unroll
    for (int i = 0; i < 2; ++i) {
        const int q = (i * 8 + w) * 64 + lane;
        r_[i] = q >> 3;
        c8_[i] = (q & 7) ^ (r_[i] & 7);
    }

    const signed char* Asrc0 = Xq + (size_t)row0 * K_DIM;
    const signed char* Asrc1 = Xq + (size_t)(row0 + 128) * K_DIM;

    // stage A tile (32 KB) at kbyte into buf b (2 halves x 16 KB)
    auto stageA = [&](int kbyte, int b) {
        const int base = b * 16384;
        GLD16(Asrc0 + (size_t)r_[0] * K_DIM + kbyte + c8_[0] * 16, lds + base + (0 * 8 + w) * 512);
        GLD16(Asrc0 + (size_t)r_[1] * K_DIM + kbyte + c8_[1] * 16, lds + base + (1 * 8 + w) * 512);
        GLD16(Asrc1 + (size_t)r_[0] * K_DIM + kbyte + c8_[0] * 16, lds + base + 8192 + (0 * 8 + w) * 512);
        GLD16(Asrc1 + (size_t)r_[1] * K_DIM + kbyte + c8_[1] * 16, lds + base + 8192 + (1 * 8 + w) * 512);
    };

// A frag read (R9-verified): row stride 64 ushorts = 128 B; chunk = (kk*2+khalf)^rswz
#define RD_A(m, kk, base) (*(const int32x4*)&lds[(base) + ((m) * 32 + lrow) * 64 + ((((kk) * 2 + khalf) ^ rswz) * 8)])

    // B per-lane bases: col = col0 + wc + n*32 + lrow, k-chunk = khalf*16
    const signed char* Bp0 = Wq + (size_t)(col0 + wc + lrow) * K_DIM + khalf * 16;
    const signed char* Bp1 = Bp0 + (size_t)32 * K_DIM;

    int32x16 acc[4][2] = {};
    int32x4 bE[2][4], bO[2][4];   // [n][kk], static double-buffer

    // ---- prologue: B[0] -> bE; stage A[0]->buf0, A[1]->buf1; certify B0+A0 ----
#pragma unroll
    for (int kk = 0; kk < 4; ++kk) {
        bE[0][kk] = *(const int32x4*)&Bp0[kk * 32];
        bE[1][kk] = *(const int32x4*)&Bp1[kk * 32];
    }
    stageA(0, 0);
    stageA(BKB, 1);
    VMCNT(4);   // drains B0(8)+A0(4); A1(4) in flight
    BAR();

#define TILE_BODY(T, CUR, NXT)                                                                     \
    do {                                                                                           \
        const int t_ = (T);                                                                        \
        const int abase = (t_ % 3) * 16384 + whalfA * 8192;                                        \
        if (t_ + 1 < NT) {                                                                         \
            _Pragma("unroll") for (int kk = 0; kk < 4; ++kk) {                                     \
                NXT[0][kk] = *(const int32x4*)&Bp0[(t_ + 1) * BKB + kk * 32];                      \
                NXT[1][kk] = *(const int32x4*)&Bp1[(t_ + 1) * BKB + kk * 32];                      \
            }                                                                                      \
        }                                                                                          \
        if (t_ + 2 < NT) stageA((t_ + 2) * BKB, (t_ + 2) % 3);                                     \
        _Pragma("unroll") for (int kk = 0; kk < 4; ++kk) {                                         \
            int32x4 af[4];                                                                         \
            _Pragma("unroll") for (int m = 0; m < 4; ++m) af[m] = RD_A(m, kk, abase);              \
            __builtin_amdgcn_s_setprio(1);                                                         \
            _Pragma("unroll") for (int m = 0; m < 4; ++m) {                                        \
                acc[m][0] = __builtin_amdgcn_mfma_i32_32x32x32_i8(af[m], CUR[0][kk], acc[m][0], 0, 0, 0); \
                acc[m][1] = __builtin_amdgcn_mfma_i32_32x32x32_i8(af[m], CUR[1][kk], acc[m][1], 0, 0, 0); \
            }                                                                                      \
            __builtin_amdgcn_s_setprio(0);                                                         \
        }                                                                                          \
        if (t_ < NT - 2) { VMCNT(4); } else { VMCNT(0); }                                          \
        BAR();                                                                                     \
    } while (0)

    for (int t = 0; t < NT; t += 2) {
        TILE_BODY(t, bE, bO);
        TILE_BODY(t + 1, bO, bE);
    }
#undef TILE_BODY

    // epilogue: Cb = bf16( acc * scale[col] )   (32x32 C/D: col=lane&31, row=(r&3)+8*(r>>2)+4*khalf)
    const int ccolb = col0 + wc + lrow;
    const int crowb = row0 + wr + 4 * khalf;
#pragma unroll
    for (int n = 0; n < 2; ++n) {
        const float sc = scale[ccolb + n * 32];
#pragma unroll
        for (int m = 0; m < 4; ++m) {
#pragma unroll
            for (int r = 0; r < 16; ++r) {
                const int row = crowb + m * 32 + (r & 3) + 8 * (r >> 2);
                const float v = (float)acc[m][n][r] * sc;
                Cb[(size_t)row * N_DIM + ccolb + n * 32] = f2bf(v);
            }
        }
    }
#undef RD_A
}

// ---------------- Mobius epilogue: out = srow * Cb * gain(norm(srow*Cb)) ----------------
__global__ __launch_bounds__(256) void mobius_bf16(const ushort* __restrict__ Cb,
                                                   const float* __restrict__ srow,
                                                   float* __restrict__ out) {
    const int row = blockIdx.x;
    const ushort* p = Cb + (size_t)row * N_DIM;
    float* q = out + (size_t)row * N_DIM;
    const int t = threadIdx.x;
    const float s = srow[row];

    typedef __attribute__((ext_vector_type(8))) short short8;
    short8 v = *(const short8*)&p[t * 8];
    float f[8];
#pragma unroll
    for (int j = 0; j < 8; ++j) {
        const uint32_t u = ((uint32_t)(uint16_t)v[j]) << 16;
        f[j] = __builtin_bit_cast(float, u);
    }
    float ss = 0.f;
#pragma unroll
    for (int j = 0; j < 8; ++j) ss += f[j] * f[j];
#pragma unroll
    for (int off = 1; off < 64; off <<= 1) ss += __shfl_xor(ss, off);
    __shared__ float wsum[4];
    if ((t & 63) == 0) wsum[t >> 6] = ss;
    __syncthreads();
    const float tot = (wsum[0] + wsum[1] + wsum[2] + wsum[3]) * s * s;
    const float vn = fmaxf(sqrtf(tot), 1e-7f);
    const float tf = tanhf(vn) / (vn + 1e-7f);
    const float on = fmaxf(tf * vn, 1e-7f);
    const float g = s * tf * fminf(0.99f / on, 1.0f);
    float4v o0, o1;
#pragma unroll
    for (int j = 0; j < 4; ++j) { o0[j] = f[j] * g; o1[j] = f[4 + j] * g; }
    *(float4v*)&q[t * 8] = o0;
    *(float4v*)&q[t * 8 + 4] = o1;
}

extern "C" void kernel_launch(void* const* d_in, const int* in_sizes, int n_in,
                              void* d_out, int out_size, void* d_ws, size_t ws_size,
                              hipStream_t stream) {
    const float* x = (const float*)d_in[0];
    const float* w = (const float*)d_in[1];
    const float* scale = (const float*)d_in[2];
    float* out = (float*)d_out;

    // ws layout: Wq @0 (4 MB), Xq @4M (16 MB), srow @20971520 (32 KB), Cb @21037056 (32 MB)
    signed char* Wq = (signed char*)d_ws;
    signed char* Xq = (signed char*)d_ws + 4194304;
    float* srow = (float*)((char*)d_ws + 20971520);
    ushort* Cb = (ushort*)((char*)d_ws + 21037056);

    transpose_w_i8<<<dim3(64 * 64), dim3(256), 0, stream>>>(w, Wq);
    quant_x<<<dim3(M_DIM), dim3(256), 0, stream>>>(x, Xq, srow);
    gemm_i8<<<dim3((M_DIM / BM) * (N_DIM / BN)), dim3(512), 0, stream>>>(Xq, Wq, scale, Cb);
    mobius_bf16<<<dim3(M_DIM), dim3(256), 0, stream>>>(Cb, srow, out);
}

// Round 14
// 80.980 us; speedup vs baseline: 1.1627x; 1.1627x over previous
//
#include <hip/hip_runtime.h>
#include <hip/hip_bf16.h>
#include <stdint.h>
#include <math.h>

// TernaryMobiusLinear: out = mobius( (x @ W) * scale ), x 8192x2048 fp32, W ternary.
// Path: x -> i8 per-row quant; W -> i8 exact; 32x32x32 i8 MFMA GEMM (i32 accum exact);
// bf16 intermediate C; Mobius epilogue kernel. [R9-verified optimum: 81.5 us total]
#define M_DIM 8192
#define K_DIM 2048
#define N_DIM 2048

#define BM 256
#define BN 256
#define BKB 128            // K-tile bytes; row = 128 B = 8 x 16B chunks
#define NT (K_DIM / BKB)   // 16

typedef __attribute__((ext_vector_type(4))) int int32x4;
typedef __attribute__((ext_vector_type(16))) int int32x16;
typedef __attribute__((ext_vector_type(4))) float float4v;

__device__ __forceinline__ ushort f2bf(float f) {
    uint32_t u = __builtin_bit_cast(uint32_t, f);
    u = (u + 0x7fffu + ((u >> 16) & 1u)) >> 16;
    return (ushort)u;
}

#define GLD16(gp, lp)                                                          \
    __builtin_amdgcn_global_load_lds(                                          \
        (const __attribute__((address_space(1))) void*)(gp),                   \
        (__attribute__((address_space(3))) void*)(lp), 16, 0, 0)

#define BAR()                                                                  \
    do {                                                                       \
        asm volatile("" ::: "memory");                                         \
        __builtin_amdgcn_s_barrier();                                          \
        asm volatile("" ::: "memory");                                         \
    } while (0)

#define VMCNT(n) asm volatile("s_waitcnt vmcnt(" #n ")" ::: "memory")

// ---------------- prepass 1: W (K x N fp32 ternary) -> Wq (N x K i8, transposed) ----------
__global__ __launch_bounds__(256) void transpose_w_i8(const float* __restrict__ W,
                                                      signed char* __restrict__ Wq) {
    __shared__ float tile[32][33];
    const int tb = blockIdx.x;
    const int kb = (tb & 63) * 32;
    const int nb = (tb >> 6) * 32;
    const int tx = threadIdx.x & 31;
    const int ty4 = (threadIdx.x >> 5) * 4;
#pragma unroll
    for (int i = 0; i < 4; i++)
        tile[ty4 + i][tx] = W[(size_t)(kb + ty4 + i) * N_DIM + nb + tx];
    __syncthreads();
    const int r = threadIdx.x >> 3;
    const int c4 = threadIdx.x & 7;
    uint32_t pk = 0;
#pragma unroll
    for (int j = 0; j < 4; j++) {
        const int q = (int)tile[c4 * 4 + j][r];
        pk |= (uint32_t)(q & 255) << (8 * j);
    }
    *(uint32_t*)&Wq[(size_t)(nb + r) * K_DIM + kb + c4 * 4] = pk;
}

// ---------------- prepass 2: x fp32 -> i8 with per-row scale ----------------
__global__ __launch_bounds__(256) void quant_x(const float* __restrict__ X,
                                               signed char* __restrict__ Xq,
                                               float* __restrict__ srow) {
    const int row = blockIdx.x;
    const int t = threadIdx.x;
    const float* p = X + (size_t)row * K_DIM;
    float4v a = *(const float4v*)&p[t * 8];
    float4v b = *(const float4v*)&p[t * 8 + 4];
    float m = 0.f;
#pragma unroll
    for (int j = 0; j < 4; j++) m = fmaxf(m, fmaxf(fabsf(a[j]), fabsf(b[j])));
#pragma unroll
    for (int off = 1; off < 64; off <<= 1) m = fmaxf(m, __shfl_xor(m, off));
    __shared__ float wm[4];
    if ((t & 63) == 0) wm[t >> 6] = m;
    __syncthreads();
    float bm = fmaxf(fmaxf(wm[0], wm[1]), fmaxf(wm[2], wm[3]));
    bm = fmaxf(bm, 1e-8f);
    const float inv = 127.f / bm;
    uint32_t lo = 0, hi = 0;
#pragma unroll
    for (int j = 0; j < 4; j++) {
        const int qa = __float2int_rn(a[j] * inv);
        const int qb = __float2int_rn(b[j] * inv);
        lo |= (uint32_t)(qa & 255) << (8 * j);
        hi |= (uint32_t)(qb & 255) << (8 * j);
    }
    uint32_t* q = (uint32_t*)&Xq[(size_t)row * K_DIM + t * 8];
    q[0] = lo;
    q[1] = hi;
    if (t == 0) srow[row] = bm / 127.f;
}

// ---------------- GEMM: Cb = bf16( (Xq @ Wq^T) * scale ), i32 accum exact ----------------
// 256x256 tile, BKB=128, 8 waves (2M x 4N), per-wave C = 128x64 = 4x2 frags of 32x32.
// mfma_i32_32x32x32_i8: A/B 16B/lane (row|col = lane&31, k = (lane>>5)*16+[0..16)),
// C/D: col=lane&31, row=(reg&3)+8*(reg>>2)+4*(lane>>5)  [m74/m101].
// Free-run schedule (R7-verified): one barrier per K-tile; stage tile t+1 at tile
// top into t-1's slots; 24 ds_read + 32 MFMA free-run; VMCNT(0) BEFORE tile-end BAR.
__global__ __launch_bounds__(512, 1) void gemm_i8(const signed char* __restrict__ Xq,
                                                  const signed char* __restrict__ Wq,
                                                  const float* __restrict__ scale,
                                                  ushort* __restrict__ Cb) {
    __shared__ __align__(16) ushort lds[65536];   // 128 KiB: A [0,32768), B [32768,65536) (ushort units)

    const int tid = threadIdx.x;
    const int w = tid >> 6;            // wave 0..7
    const int lane = tid & 63;
    const int lrow = lane & 31;        // row|col within 32x32 frag
    const int khalf = lane >> 5;       // 0..1: which 16B chunk within K=32
    const int rswz = lrow & 7;         // read-side XOR (chunk units)

    // XCD-chunked bijective swizzle (nwg=256, 8 XCDs)
    const int bid = blockIdx.x;
    const int wg = (bid & 7) * 32 + (bid >> 3);
    const int mt = wg >> 3;            // 0..31
    const int nt = wg & 7;             // 0..7
    const int row0 = mt * BM;
    const int col0 = nt * BN;

    const int wr = (w >> 2) * 128;     // wave M offset
    const int wc = (w & 3) * 64;       // wave N offset
    const int whalfA = w >> 2;
    const int whalfB = (w & 3) >> 1;
    const int wrB = (w & 1) * 64;      // row offset within B half

    int r_[2], c8_[2];
#pragma unroll
    for (int i = 0; i < 2; ++i) {
        const int q = (i * 8 + w) * 64 + lane;
        r_[i] = q >> 3;
        c8_[i] = (q & 7) ^ (r_[i] & 7);
    }

    auto stage2 = [&](const signed char* sb, int ldsbase) {
        GLD16(sb + (size_t)r_[0] * K_DIM + c8_[0] * 16, lds + ldsbase + (0 * 8 + w) * 512);
        GLD16(sb + (size_t)r_[1] * K_DIM + c8_[1] * 16, lds + ldsbase + (1 * 8 + w) * 512);
    };

// ushort-unit indexing: row stride 64 ushorts = 128 B; chunk = 8 ushorts = 16 B.
#define RD_A(m, kk, base) (*(const int32x4*)&lds[(base) + ((m) * 32 + lrow) * 64 + ((((kk) * 2 + khalf) ^ rswz) * 8)])
#define RD_B(n, kk, base) (*(const int32x4*)&lds[(base) + (wrB + (n) * 32 + lrow) * 64 + ((((kk) * 2 + khalf) ^ rswz) * 8)])

    int32x16 acc[4][2] = {};

    const signed char* Asrc0 = Xq + (size_t)row0 * K_DIM;
    const signed char* Asrc1 = Xq + (size_t)(row0 + 128) * K_DIM;
    const signed char* Bsrc0 = Wq + (size_t)col0 * K_DIM;
    const signed char* Bsrc1 = Wq + (size_t)(col0 + 128) * K_DIM;

    // prologue: stage tile 0, drain, barrier
    stage2(Asrc0, 0 * 8192);
    stage2(Asrc1, 1 * 8192);
    stage2(Bsrc0, 32768 + 0 * 8192);
    stage2(Bsrc1, 32768 + 1 * 8192);
    VMCNT(0);
    BAR();

    for (int t = 0; t < NT; ++t) {
        const int abase = ((2 * t + whalfA) & 3) * 8192;
        const int bbase = 32768 + ((2 * t + whalfB) & 3) * 8192;
        const bool pf = (t + 1 < NT);
        const int aslot0 = ((2 * (t + 1)) & 3) * 8192;
        const int aslot1 = ((2 * (t + 1) + 1) & 3) * 8192;
        const int bslot0 = 32768 + ((2 * (t + 1)) & 3) * 8192;
        const int bslot1 = 32768 + ((2 * (t + 1) + 1) & 3) * 8192;

        // stage tile t+1 fully, earliest (into t-1's slots; max drain cover)
        if (pf) {
            stage2(Asrc0 + (t + 1) * BKB, aslot0);
            stage2(Asrc1 + (t + 1) * BKB, aslot1);
            stage2(Bsrc0 + (t + 1) * BKB, bslot0);
            stage2(Bsrc1 + (t + 1) * BKB, bslot1);
        }

        // free-run compute: 4 kk steps (K=32 each), no intra-tile barriers
#pragma unroll
        for (int kk = 0; kk < 4; ++kk) {
            int32x4 bfr[2], afr[4];
#pragma unroll
            for (int n = 0; n < 2; ++n) bfr[n] = RD_B(n, kk, bbase);
#pragma unroll
            for (int m = 0; m < 4; ++m) afr[m] = RD_A(m, kk, abase);
            __builtin_amdgcn_s_setprio(1);
#pragma unroll
            for (int m = 0; m < 4; ++m)
#pragma unroll
                for (int n = 0; n < 2; ++n)
                    acc[m][n] = __builtin_amdgcn_mfma_i32_32x32x32_i8(afr[m], bfr[n], acc[m][n], 0, 0, 0);
            __builtin_amdgcn_s_setprio(0);
        }

        // tile boundary: drain own staging BEFORE barrier (R5 lesson)
        VMCNT(0);
        BAR();
    }

    // epilogue: Cb = bf16( acc * scale[col] )   (row scale folded into mobius)
    const int ccolb = col0 + wc + lrow;           // + n*32
    const int crowb = row0 + wr + 4 * khalf;      // + m*32 + (reg&3) + 8*(reg>>2)
#pragma unroll
    for (int n = 0; n < 2; ++n) {
        const float sc = scale[ccolb + n * 32];
#pragma unroll
        for (int m = 0; m < 4; ++m) {
#pragma unroll
            for (int r = 0; r < 16; ++r) {
                const int row = crowb + m * 32 + (r & 3) + 8 * (r >> 2);
                const float v = (float)acc[m][n][r] * sc;
                Cb[(size_t)row * N_DIM + ccolb + n * 32] = f2bf(v);
            }
        }
    }
#undef RD_A
#undef RD_B
}

// ---------------- Mobius epilogue: out = srow * Cb * gain(norm(srow*Cb)) ----------------
__global__ __launch_bounds__(256) void mobius_bf16(const ushort* __restrict__ Cb,
                                                   const float* __restrict__ srow,
                                                   float* __restrict__ out) {
    const int row = blockIdx.x;
    const ushort* p = Cb + (size_t)row * N_DIM;
    float* q = out + (size_t)row * N_DIM;
    const int t = threadIdx.x;
    const float s = srow[row];

    typedef __attribute__((ext_vector_type(8))) short short8;
    short8 v = *(const short8*)&p[t * 8];
    float f[8];
#pragma unroll
    for (int j = 0; j < 8; ++j) {
        const uint32_t u = ((uint32_t)(uint16_t)v[j]) << 16;
        f[j] = __builtin_bit_cast(float, u);
    }
    float ss = 0.f;
#pragma unroll
    for (int j = 0; j < 8; ++j) ss += f[j] * f[j];
#pragma unroll
    for (int off = 1; off < 64; off <<= 1) ss += __shfl_xor(ss, off);
    __shared__ float wsum[4];
    if ((t & 63) == 0) wsum[t >> 6] = ss;
    __syncthreads();
    const float tot = (wsum[0] + wsum[1] + wsum[2] + wsum[3]) * s * s;
    const float vn = fmaxf(sqrtf(tot), 1e-7f);
    const float tf = tanhf(vn) / (vn + 1e-7f);
    const float on = fmaxf(tf * vn, 1e-7f);
    const float g = s * tf * fminf(0.99f / on, 1.0f);
    float4v o0, o1;
#pragma unroll
    for (int j = 0; j < 4; ++j) { o0[j] = f[j] * g; o1[j] = f[4 + j] * g; }
    *(float4v*)&q[t * 8] = o0;
    *(float4v*)&q[t * 8 + 4] = o1;
}

extern "C" void kernel_launch(void* const* d_in, const int* in_sizes, int n_in,
                              void* d_out, int out_size, void* d_ws, size_t ws_size,
                              hipStream_t stream) {
    const float* x = (const float*)d_in[0];
    const float* w = (const float*)d_in[1];
    const float* scale = (const float*)d_in[2];
    float* out = (float*)d_out;

    // ws layout: Wq @0 (4 MB), Xq @4M (16 MB), srow @20M (32 KB), Cb @20M+64K (32 MB)
    signed char* Wq = (signed char*)d_ws;
    signed char* Xq = (signed char*)d_ws + 4194304;
    float* srow = (float*)((char*)d_ws + 20971520);
    ushort* Cb = (ushort*)((char*)d_ws + 21037056);

    transpose_w_i8<<<dim3(64 * 64), dim3(256), 0, stream>>>(w, Wq);
    quant_x<<<dim3(M_DIM), dim3(256), 0, stream>>>(x, Xq, srow);
    gemm_i8<<<dim3((M_DIM / BM) * (N_DIM / BN)), dim3(512), 0, stream>>>(Xq, Wq, scale, Cb);
    mobius_bf16<<<dim3(M_DIM), dim3(256), 0, stream>>>(Cb, srow, out);
}